// Round 6
// baseline (17.669 us; speedup 1.0000x reference)
//
#include <hip/hip_runtime.h>
#include <hip/hip_bf16.h>

// velocity = MLP(concat[zone_embedding, person_attrs, time_vec])
// GCN layers in the reference are dead code (outputs unused) -> skipped.
//
// Round-6: latency restructure of the round-5 MFMA kernel.
//  - ONE 32-zone macro-tile per wave (3125 tiles, 3128 waves): no tile loop;
//    the X global loads issue at kernel ENTRY and overlap the entire
//    preamble (time-encoder syncthreads chain + 80 scattered weight loads).
//  - Two independent 16-zone halves interleaved through all 3 layers:
//    2x MFMA ILP in every dependent section; each lgkmcnt(0) LDS drain is
//    amortized over 8 MFMAs instead of 4.
// Fragment math identical to the verified round-5 kernel (C/D map:
// col=lane&15, row=(lane>>4)*4+reg; k=8g+j used identically on A and B).

typedef __attribute__((ext_vector_type(8))) short bf16x8;
typedef __attribute__((ext_vector_type(4))) float f32x4;

#define BLK 256
#define WPB 4              // waves per block
#define H1_STRIDE 72       // bf16 elems per row: 64 + 8 pad (bank spread)
#define H2_STRIDE 40       // 32 + 8 pad

__device__ __forceinline__ short f2bf(float x) {
    union { __hip_bfloat16 h; short s; } u;
    u.h = __float2bfloat16(x);
    return u.s;
}

__global__ __launch_bounds__(BLK, 2) void zone_velocity_mfma(
    const float* __restrict__ tp,
    const float* __restrict__ emb,      // [N,32]
    const float* __restrict__ pa,       // [8]
    const float* __restrict__ Wt1, const float* __restrict__ bt1,
    const float* __restrict__ Wt2, const float* __restrict__ bt2,
    const float* __restrict__ Wd1, const float* __restrict__ bd1,  // [56,64],[64]
    const float* __restrict__ Wd2, const float* __restrict__ bd2,  // [64,32],[32]
    const float* __restrict__ Wd3, const float* __restrict__ bd3,  // [32,32],[32]
    float* __restrict__ out,            // [N,32]
    int N, int ntiles)
{
    __shared__ float s_u[16];
    __shared__ float s_tv[16];
    __shared__ float s_h1b[64];
    __shared__ __align__(16) short s_H1[WPB][32 * H1_STRIDE];
    __shared__ __align__(16) short s_H2[WPB][32 * H2_STRIDE];

    const int tidx = threadIdx.x;
    const int wave = tidx >> 6;
    const int lane = tidx & 63;
    const int c = lane & 15;   // A-row / B-col / D-col index
    const int g = lane >> 4;   // k-group (k = 8g + j)

    const int wid = blockIdx.x * WPB + wave;   // macro-tile id
    const bool active = (wid < ntiles);
    const int zb = wid * 32;

    // ---- issue X loads IMMEDIATELY (overlap with the whole preamble) ----
    // half h covers zones zb+16h .. zb+16h+15; lane reads row zb+16h+c,
    // channels 8g..8g+7. Clamp keeps inactive waves in-bounds.
    float4 xa[2][2];
    #pragma unroll
    for (int h = 0; h < 2; h++) {
        int zr = zb + 16 * h + c;
        if (zr >= N) zr = N - 1;
        const float* ep = emb + (size_t)zr * 32 + 8 * g;
        xa[h][0] = *reinterpret_cast<const float4*>(ep);
        xa[h][1] = *reinterpret_cast<const float4*>(ep + 4);
    }

    // ---- weight fragments (uniform addrs; independent of syncs) ----
    bf16x8 w1f[4];        // Wd1[0:32] -> 4 n-tiles
    bf16x8 w2f[2][2];     // Wd2: 2 k-steps x 2 n-tiles
    bf16x8 w3f[2];        // Wd3: 2 n-tiles
    #pragma unroll
    for (int tt = 0; tt < 4; tt++)
        #pragma unroll
        for (int j = 0; j < 8; j++)
            w1f[tt][j] = f2bf(Wd1[(8 * g + j) * 64 + 16 * tt + c]);
    #pragma unroll
    for (int s = 0; s < 2; s++)
        #pragma unroll
        for (int tt = 0; tt < 2; tt++)
            #pragma unroll
            for (int j = 0; j < 8; j++)
                w2f[s][tt][j] = f2bf(Wd2[(32 * s + 8 * g + j) * 32 + 16 * tt + c]);
    #pragma unroll
    for (int tt = 0; tt < 2; tt++)
        #pragma unroll
        for (int j = 0; j < 8; j++)
            w3f[tt][j] = f2bf(Wd3[(8 * g + j) * 32 + 16 * tt + c]);

    // ---- time encoder (fp32 exact; tiny) ----
    const float tval = tp[0];
    if (tidx < 16) s_u[tidx] = fmaxf(tval * Wt1[tidx] + bt1[tidx], 0.0f);
    __syncthreads();
    if (tidx < 16) {
        float a = bt2[tidx];
        #pragma unroll
        for (int k = 0; k < 16; k++) a = fmaf(s_u[k], Wt2[k * 16 + tidx], a);
        s_tv[tidx] = a;  // no relu on second time layer
    }
    __syncthreads();

    // ---- h1 base: bd1 + person/time @ Wd1[32:56] (zone-uniform, fp32) ----
    if (tidx < 64) {
        float a = bd1[tidx];
        #pragma unroll
        for (int k = 0; k < 8; k++)
            a = fmaf(pa[k], Wd1[(32 + k) * 64 + tidx], a);
        #pragma unroll
        for (int k = 0; k < 16; k++)
            a = fmaf(s_tv[k], Wd1[(40 + k) * 64 + tidx], a);
        s_h1b[tidx] = a;
    }
    __syncthreads();

    // ---- per-lane biases ----
    float h1b[4];
    #pragma unroll
    for (int tt = 0; tt < 4; tt++) h1b[tt] = s_h1b[16 * tt + c];
    float b2r[2] = { bd2[c], bd2[16 + c] };
    float b3r[2] = { bd3[c], bd3[16 + c] };

    if (!active) return;   // after last __syncthreads: safe

    short* H1 = s_H1[wave];
    short* H2 = s_H2[wave];

    // ---- convert X to bf16 fragments ----
    bf16x8 af[2];
    #pragma unroll
    for (int h = 0; h < 2; h++) {
        af[h][0] = f2bf(xa[h][0].x); af[h][1] = f2bf(xa[h][0].y);
        af[h][2] = f2bf(xa[h][0].z); af[h][3] = f2bf(xa[h][0].w);
        af[h][4] = f2bf(xa[h][1].x); af[h][5] = f2bf(xa[h][1].y);
        af[h][6] = f2bf(xa[h][1].z); af[h][7] = f2bf(xa[h][1].w);
    }

    // ---- layer 1: H1[32,64] = relu(X @ Wd1[0:32] + h1b)  (8 indep MFMAs) ----
    f32x4 acc1[2][4];
    #pragma unroll
    for (int h = 0; h < 2; h++)
        #pragma unroll
        for (int tt = 0; tt < 4; tt++) {
            f32x4 ci; ci[0] = ci[1] = ci[2] = ci[3] = h1b[tt];
            acc1[h][tt] = __builtin_amdgcn_mfma_f32_16x16x32_bf16(
                af[h], w1f[tt], ci, 0, 0, 0);
        }
    #pragma unroll
    for (int h = 0; h < 2; h++)
        #pragma unroll
        for (int tt = 0; tt < 4; tt++)
            #pragma unroll
            for (int r = 0; r < 4; r++)
                H1[(16 * h + 4 * g + r) * H1_STRIDE + 16 * tt + c] =
                    f2bf(fmaxf(acc1[h][tt][r], 0.0f));

    __builtin_amdgcn_wave_barrier();
    asm volatile("s_waitcnt lgkmcnt(0)" ::: "memory");
    __builtin_amdgcn_sched_barrier(0);

    // ---- layer 2: H2[32,32] = relu(H1 @ Wd2 + bd2)  (8 MFMAs, 2x ILP) ----
    f32x4 acc2[2][2];
    #pragma unroll
    for (int h = 0; h < 2; h++)
        #pragma unroll
        for (int tt = 0; tt < 2; tt++) {
            f32x4 ci; ci[0] = ci[1] = ci[2] = ci[3] = b2r[tt];
            acc2[h][tt] = ci;
        }
    #pragma unroll
    for (int s = 0; s < 2; s++)
        #pragma unroll
        for (int h = 0; h < 2; h++) {
            bf16x8 a2 = *reinterpret_cast<const bf16x8*>(
                H1 + (16 * h + c) * H1_STRIDE + 32 * s + 8 * g);
            #pragma unroll
            for (int tt = 0; tt < 2; tt++)
                acc2[h][tt] = __builtin_amdgcn_mfma_f32_16x16x32_bf16(
                    a2, w2f[s][tt], acc2[h][tt], 0, 0, 0);
        }
    #pragma unroll
    for (int h = 0; h < 2; h++)
        #pragma unroll
        for (int tt = 0; tt < 2; tt++)
            #pragma unroll
            for (int r = 0; r < 4; r++)
                H2[(16 * h + 4 * g + r) * H2_STRIDE + 16 * tt + c] =
                    f2bf(fmaxf(acc2[h][tt][r], 0.0f));

    __builtin_amdgcn_wave_barrier();
    asm volatile("s_waitcnt lgkmcnt(0)" ::: "memory");
    __builtin_amdgcn_sched_barrier(0);

    // ---- layer 3: O[32,32] = H2 @ Wd3 + bd3  (4 MFMAs) ----
    f32x4 acc3[2][2];
    #pragma unroll
    for (int h = 0; h < 2; h++) {
        bf16x8 a3 = *reinterpret_cast<const bf16x8*>(
            H2 + (16 * h + c) * H2_STRIDE + 8 * g);
        #pragma unroll
        for (int tt = 0; tt < 2; tt++) {
            f32x4 ci; ci[0] = ci[1] = ci[2] = ci[3] = b3r[tt];
            acc3[h][tt] = __builtin_amdgcn_mfma_f32_16x16x32_bf16(
                a3, w3f[tt], ci, 0, 0, 0);
        }
    }

    // ---- store: zone = zb + 16h + 4g + r, channels c and 16+c ----
    #pragma unroll
    for (int h = 0; h < 2; h++)
        #pragma unroll
        for (int r = 0; r < 4; r++) {
            const int zo = zb + 16 * h + 4 * g + r;
            if (zo < N) {
                float* op = out + (size_t)zo * 32;
                op[c]      = acc3[h][0][r];
                op[16 + c] = acc3[h][1][r];
            }
        }
}

extern "C" void kernel_launch(void* const* d_in, const int* in_sizes, int n_in,
                              void* d_out, int out_size, void* d_ws, size_t ws_size,
                              hipStream_t stream) {
    // setup_inputs() order:
    //  0 t, 1 zone_embedding, 2 zone_features, 3 person_attrs, 4 edge_index,
    //  5 W1, 6 b1, 7 W2, 8 b2, 9 Wt1, 10 bt1, 11 Wt2, 12 bt2,
    // 13 Wd1, 14 bd1, 15 Wd2, 16 bd2, 17 Wd3, 18 bd3
    const float* t   = (const float*)d_in[0];
    const float* emb = (const float*)d_in[1];
    const float* pa  = (const float*)d_in[3];
    const float* Wt1 = (const float*)d_in[9];
    const float* bt1 = (const float*)d_in[10];
    const float* Wt2 = (const float*)d_in[11];
    const float* bt2 = (const float*)d_in[12];
    const float* Wd1 = (const float*)d_in[13];
    const float* bd1 = (const float*)d_in[14];
    const float* Wd2 = (const float*)d_in[15];
    const float* bd2 = (const float*)d_in[16];
    const float* Wd3 = (const float*)d_in[17];
    const float* bd3 = (const float*)d_in[18];

    const int N = in_sizes[1] / 32;          // 100000
    const int ntiles = (N + 31) / 32;        // 3125 macro-tiles (exact: 32*3125)
    float* out = (float*)d_out;

    const int blocks = (ntiles + WPB - 1) / WPB;   // 782 -> 3128 waves
    zone_velocity_mfma<<<blocks, BLK, 0, stream>>>(
        t, emb, pa, Wt1, bt1, Wt2, bt2,
        Wd1, bd1, Wd2, bd2, Wd3, bd3, out, N, ntiles);
}